// Round 13
// baseline (6293.010 us; speedup 1.0000x reference)
//
#include <hip/hip_runtime.h>

#define ROWS 32768      // B*T
#define D 512
#define NCODES 8192
#define KC 384          // OpenBLAS sgemm kc panel split (verified exact, rounds 4-12)
#define NTILES 64       // 8192 codes / 128
#define MAXT 16

typedef _Float16 h8 __attribute__((ext_vector_type(8)));
typedef float f4v __attribute__((ext_vector_type(4)));

// numpy pairwise f32 sum of squares of a 512-float row (verified exact).
__device__ __forceinline__ float np_sumsq_512(const float* __restrict__ p) {
    float blk[4];
#pragma unroll
    for (int b = 0; b < 4; ++b) {
        const float* q = p + b * 128;
        float r[8];
#pragma unroll
        for (int j = 0; j < 8; ++j) r[j] = __fmul_rn(q[j], q[j]);
#pragma unroll
        for (int i = 1; i < 16; ++i)
#pragma unroll
            for (int j = 0; j < 8; ++j)
                r[j] = __fadd_rn(r[j], __fmul_rn(q[i * 8 + j], q[i * 8 + j]));
        blk[b] = __fadd_rn(__fadd_rn(__fadd_rn(r[0], r[1]), __fadd_rn(r[2], r[3])),
                           __fadd_rn(__fadd_rn(r[4], r[5]), __fadd_rn(r[6], r[7])));
    }
    return __fadd_rn(__fadd_rn(blk[0], blk[1]), __fadd_rn(blk[2], blk[3]));
}

// ---------------- kernel 1: row sums of squares + sum|x| ----------------
__global__ void k_rowsums(const float* __restrict__ zE, const float* __restrict__ cb,
                          float* __restrict__ sq, float* __restrict__ e2,
                          float* __restrict__ sabs) {
    int row = blockIdx.x * 64 + threadIdx.x;          // 640 x 64 = 40960
    if (row < ROWS) {
        const float* p = zE + (size_t)row * D;
        sq[row] = np_sumsq_512(p);
        float sa = 0.0f;
#pragma unroll 8
        for (int k = 0; k < D; ++k) sa += fabsf(p[k]);
        sabs[row] = sa;
    } else {
        e2[row - ROWS] = np_sumsq_512(cb + (size_t)(row - ROWS) * D);
    }
}

// ---------------- kernel 2: f32 -> f16 conversion (cb scaled by 2^12) ----------------
__global__ void k_half(const float* __restrict__ zE, const float* __restrict__ cb,
                       _Float16* __restrict__ zh, _Float16* __restrict__ ch) {
    int i = (blockIdx.x * 256 + threadIdx.x) * 8;     // 10240 blocks
    if (i < ROWS * D) {
        float4 u = *(const float4*)(zE + i);
        float4 v = *(const float4*)(zE + i + 4);
        h8 o = {(_Float16)u.x, (_Float16)u.y, (_Float16)u.z, (_Float16)u.w,
                (_Float16)v.x, (_Float16)v.y, (_Float16)v.z, (_Float16)v.w};
        *(h8*)(zh + i) = o;
    } else {
        int j = i - ROWS * D;
        float4 u = *(const float4*)(cb + j);
        float4 v = *(const float4*)(cb + j + 4);
        h8 o = {(_Float16)(u.x * 4096.0f), (_Float16)(u.y * 4096.0f),
                (_Float16)(u.z * 4096.0f), (_Float16)(u.w * 4096.0f),
                (_Float16)(v.x * 4096.0f), (_Float16)(v.y * 4096.0f),
                (_Float16)(v.z * 4096.0f), (_Float16)(v.w * 4096.0f)};
        *(h8*)(ch + j) = o;
    }
}

// approx distance (deterministic)
__device__ __forceinline__ float dapprox(float s, float accv, float ecv) {
    float m = __fmul_rn(accv, 0.000244140625f);       // exact /4096
    return __fadd_rn(__fsub_rn(s, __fmul_rn(2.0f, m)), ecv);
}

// ---------------- kernel 3: fp16 MFMA distance pass -> per-tile minima ----------------
// block = 4 waves; wave tile 64 rows x 128 codes; mfma_f32_16x16x32_f16.
// D frag: col = lane&15, row = (lane>>4)*4 + j (verified round 12, absmax 0).
// Writes tmin[row][tile] = min d~ over the tile's 128 codes. No atomics.
__global__ __launch_bounds__(256, 2)
void k_mfma_min(const _Float16* __restrict__ zh, const _Float16* __restrict__ ch,
                const float* __restrict__ sq, const float* __restrict__ e2,
                float* __restrict__ tmin) {
    const int p    = blockIdx.x;                      // 0..8191
    const int ct   = (p & 7) * 8 + ((p >> 3) & 7);    // code tile 0..63 (XCD-local)
    const int rt   = p >> 6;                          // row tile 0..127
    const int wave = threadIdx.x >> 6;
    const int lane = threadIdx.x & 63;
    const int l15  = lane & 15;
    const int lk   = lane >> 4;
    const int rw   = rt * 256 + wave * 64;
    const int cw   = ct * 128;

    f4v acc[4][8];
#pragma unroll
    for (int a = 0; a < 4; ++a)
#pragma unroll
        for (int b = 0; b < 8; ++b) acc[a][b] = (f4v){0.f, 0.f, 0.f, 0.f};

#pragma unroll 2
    for (int k0 = 0; k0 < D; k0 += 32) {
        h8 bf[8];
#pragma unroll
        for (int b = 0; b < 8; ++b)
            bf[b] = *(const h8*)(ch + (size_t)(cw + b * 16 + l15) * D + k0 + lk * 8);
#pragma unroll
        for (int a = 0; a < 4; ++a) {
            h8 af = *(const h8*)(zh + (size_t)(rw + a * 16 + l15) * D + k0 + lk * 8);
#pragma unroll
            for (int b = 0; b < 8; ++b)
                acc[a][b] = __builtin_amdgcn_mfma_f32_16x16x32_f16(af, bf[b], acc[a][b], 0, 0, 0);
        }
    }

#pragma unroll
    for (int a = 0; a < 4; ++a) {
        const int r0 = rw + a * 16 + lk * 4;
        float s0 = sq[r0 + 0], s1 = sq[r0 + 1], s2 = sq[r0 + 2], s3 = sq[r0 + 3];
        float rm[4] = {INFINITY, INFINITY, INFINITY, INFINITY};
#pragma unroll
        for (int b = 0; b < 8; ++b) {
            float ecv = e2[cw + b * 16 + l15];
            rm[0] = fminf(rm[0], dapprox(s0, acc[a][b][0], ecv));
            rm[1] = fminf(rm[1], dapprox(s1, acc[a][b][1], ecv));
            rm[2] = fminf(rm[2], dapprox(s2, acc[a][b][2], ecv));
            rm[3] = fminf(rm[3], dapprox(s3, acc[a][b][3], ecv));
        }
#pragma unroll
        for (int jj = 0; jj < 4; ++jj) {
            float v = rm[jj];
            v = fminf(v, __shfl_xor(v, 1));
            v = fminf(v, __shfl_xor(v, 2));
            v = fminf(v, __shfl_xor(v, 4));
            v = fminf(v, __shfl_xor(v, 8));
            if (l15 == 0) tmin[(size_t)(r0 + jj) * NTILES + ct] = v;
        }
    }
}

// ---------------- kernel 4: select qualifying tiles per row ----------------
__global__ void k_select(const float* __restrict__ tmin, const float* __restrict__ sabs,
                         int* __restrict__ tcnt, int* __restrict__ tlist) {
    int row = blockIdx.x * 256 + threadIdx.x;
    if (row >= ROWS) return;
    const float* t = tmin + (size_t)row * NTILES;
    float g = t[0];
#pragma unroll 8
    for (int i = 1; i < NTILES; ++i) g = fminf(g, t[i]);
    float thr = g + (sabs[row] * 8e-7f + 6e-4f);      // WIN = 2*err bound
    int n = 0;
    for (int i = 0; i < NTILES; ++i)
        if (t[i] <= thr) { if (n < MAXT) tlist[(size_t)row * MAXT + n] = i; ++n; }
    tcnt[row] = n;
}

// exact distance: verified dual-chain, x from LDS, e from global
__device__ __forceinline__ float exact_d(const float* __restrict__ xs,
                                         const float* __restrict__ er,
                                         float s, float ev) {
    float m1 = 0.0f, m2 = 0.0f;
#pragma unroll 8
    for (int k = 0; k < KC; ++k) m1 = __builtin_fmaf(xs[k], er[k], m1);
#pragma unroll 8
    for (int k = KC; k < D; ++k) m2 = __builtin_fmaf(xs[k], er[k], m2);
    float m = __fadd_rn(m1, m2);
    return __fadd_rn(__fsub_rn(s, __fmul_rn(2.0f, m)), ev);
}

// ---------------- kernel 5: exact rescore of qualifying tiles -> ids ----------------
// 1 wave per row; lane handles 2 codes per tile; lexicographic (d, idx) reduce.
__global__ __launch_bounds__(256)
void k_rescore(const float* __restrict__ zE, const float* __restrict__ cb,
               const float* __restrict__ sq, const float* __restrict__ e2,
               const int* __restrict__ tcnt, const int* __restrict__ tlist,
               int* __restrict__ ids, float* __restrict__ outIds) {
    __shared__ float xs[4][D];
    const int wave = threadIdx.x >> 6;
    const int lane = threadIdx.x & 63;
    const int row  = blockIdx.x * 4 + wave;

    const float* xr = zE + (size_t)row * D;
    *(float4*)&xs[wave][lane * 8]     = *(const float4*)(xr + lane * 8);
    *(float4*)&xs[wave][lane * 8 + 4] = *(const float4*)(xr + lane * 8 + 4);
    __syncthreads();

    float s = sq[row];
    int   n = tcnt[row];
    float bd = INFINITY;
    int   bi = NCODES - 1;
    if (n <= MAXT) {
        for (int t = 0; t < n; ++t) {
            int tile = tlist[(size_t)row * MAXT + t];
#pragma unroll
            for (int h = 0; h < 2; ++h) {
                int c = tile * 128 + h * 64 + lane;
                float d = exact_d(xs[wave], cb + (size_t)c * D, s, e2[c]);
                if (d < bd || (d == bd && c < bi)) { bd = d; bi = c; }
            }
        }
    } else {                                          // sound fallback (never expected)
        for (int c0 = 0; c0 < NCODES; c0 += 64) {
            int c = c0 + lane;
            float d = exact_d(xs[wave], cb + (size_t)c * D, s, e2[c]);
            if (d < bd || (d == bd && c < bi)) { bd = d; bi = c; }
        }
    }
#pragma unroll
    for (int off = 32; off; off >>= 1) {
        float v2 = __shfl_xor(bd, off);
        int   x2 = __shfl_xor(bi, off);
        if (v2 < bd || (v2 == bd && x2 < bi)) { bd = v2; bi = x2; }
    }
    if (lane == 0) {
        int b = bi < 0 ? 0 : (bi > NCODES - 1 ? NCODES - 1 : bi);
        ids[row] = b;
        outIds[row] = (float)b;
    }
}

// ---------------- kernel 6: gather z_q_st (f32) + loss partials (verified) ----------------
__global__ void k_gather(const float* __restrict__ zE, const float* __restrict__ cb,
                         const int* __restrict__ ids, float* __restrict__ outZ,
                         double* __restrict__ lossPart) {
    const int tid = threadIdx.x;
    double acc = 0.0;
#pragma unroll
    for (int it = 0; it < 4; ++it) {
        int chunk = blockIdx.x * 256 + tid + it * 1048576;
        int row   = chunk >> 7;
        int koff  = (chunk & 127) << 2;
        int id    = ids[row];
        id = id < 0 ? 0 : (id > NCODES - 1 ? NCODES - 1 : id);
        float4 ze = *(const float4*)(zE + ((size_t)row << 9) + koff);
        float4 zq = *(const float4*)(cb + ((size_t)id << 9) + koff);
        float d0 = __fsub_rn(zq.x, ze.x);
        float d1 = __fsub_rn(zq.y, ze.y);
        float d2 = __fsub_rn(zq.z, ze.z);
        float d3 = __fsub_rn(zq.w, ze.w);
        float4 v;
        v.x = __fadd_rn(ze.x, d0);
        v.y = __fadd_rn(ze.y, d1);
        v.z = __fadd_rn(ze.z, d2);
        v.w = __fadd_rn(ze.w, d3);
        *reinterpret_cast<float4*>(outZ + ((size_t)chunk << 2)) = v;
        acc += (double)d0 * d0 + (double)d1 * d1 + (double)d2 * d2 + (double)d3 * d3;
    }
    for (int off = 32; off; off >>= 1) acc += __shfl_down(acc, off);
    __shared__ double sred[4];
    if ((tid & 63) == 0) sred[tid >> 6] = acc;
    __syncthreads();
    if (tid == 0) lossPart[blockIdx.x] = (sred[0] + sred[1]) + (sred[2] + sred[3]);
}

// ---------------- kernel 7: final loss (verified) ----------------
__global__ void k_loss(const double* __restrict__ lossPart, float* __restrict__ outLoss) {
    const int tid = threadIdx.x;
    double acc = 0.0;
    for (int i = tid; i < 4096; i += 256) acc += lossPart[i];
    for (int off = 32; off; off >>= 1) acc += __shfl_down(acc, off);
    __shared__ double sred[4];
    if ((tid & 63) == 0) sred[tid >> 6] = acc;
    __syncthreads();
    if (tid == 0) {
        double mean = ((sred[0] + sred[1]) + (sred[2] + sred[3])) / 16777216.0;
        float cl = (float)mean;
        *outLoss = __fadd_rn(cl, __fmul_rn(0.25f, cl));
    }
}

extern "C" void kernel_launch(void* const* d_in, const int* in_sizes, int n_in,
                              void* d_out, int out_size, void* d_ws, size_t ws_size,
                              hipStream_t stream) {
    (void)in_sizes; (void)n_in; (void)out_size; (void)ws_size;
    const float* zE = (const float*)d_in[0];
    const float* cb = (const float*)d_in[1];
    float* out = (float*)d_out;
    char*  ws  = (char*)d_ws;
    char*  ob  = (char*)d_out;

    // ws scratch (small)
    float*  sq       = (float*)(ws + 0);              // 128 KiB
    float*  e2       = (float*)(ws + 131072);         // 32 KiB
    int*    ids      = (int*)(ws + 163840);           // 128 KiB
    float*  sabs     = (float*)(ws + 294912);         // 128 KiB
    int*    tcnt     = (int*)(ws + 425984);           // 128 KiB
    double* lossPart = (double*)(ws + 1343488);       // 32 KiB

    // big scratch inside d_out region 0 (fully overwritten by k_gather afterwards)
    _Float16* zh    = (_Float16*)(ob + 0);            // 32 MiB
    _Float16* ch    = (_Float16*)(ob + 33554432);     //  8 MiB
    float*    tmin  = (float*)(ob + 41943040);        //  8 MiB
    int*      tlist = (int*)(ob + 50331648);          //  2 MiB

    k_rowsums<<<(ROWS + NCODES) / 64, 64, 0, stream>>>(zE, cb, sq, e2, sabs);
    k_half<<<(ROWS + NCODES) * (D / 8) / 256, 256, 0, stream>>>(zE, cb, zh, ch);
    k_mfma_min<<<8192, 256, 0, stream>>>(zh, ch, sq, e2, tmin);
    k_select<<<ROWS / 256, 256, 0, stream>>>(tmin, sabs, tcnt, tlist);
    k_rescore<<<ROWS / 4, 256, 0, stream>>>(zE, cb, sq, e2, tcnt, tlist,
                                            ids, out + 16777216);
    k_gather<<<4096, 256, 0, stream>>>(zE, cb, ids, out, lossPart);
    k_loss<<<1, 256, 0, stream>>>(lossPart, out + 16777216 + 32768);
}

// Round 14
// 4622.812 us; speedup vs baseline: 1.3613x; 1.3613x over previous
//
#include <hip/hip_runtime.h>

#define ROWS 32768      // B*T
#define D 512
#define NCODES 8192
#define KC 384          // OpenBLAS sgemm kc panel split (verified exact, rounds 4-13)
#define NTILES 64       // 8192 codes / 128

typedef _Float16 h8 __attribute__((ext_vector_type(8)));
typedef float f4v __attribute__((ext_vector_type(4)));

// numpy pairwise f32 sum of squares of a 512-float row (verified exact).
__device__ __forceinline__ float np_sumsq_512(const float* __restrict__ p) {
    float blk[4];
#pragma unroll
    for (int b = 0; b < 4; ++b) {
        const float* q = p + b * 128;
        float r[8];
#pragma unroll
        for (int j = 0; j < 8; ++j) r[j] = __fmul_rn(q[j], q[j]);
#pragma unroll
        for (int i = 1; i < 16; ++i)
#pragma unroll
            for (int j = 0; j < 8; ++j)
                r[j] = __fadd_rn(r[j], __fmul_rn(q[i * 8 + j], q[i * 8 + j]));
        blk[b] = __fadd_rn(__fadd_rn(__fadd_rn(r[0], r[1]), __fadd_rn(r[2], r[3])),
                           __fadd_rn(__fadd_rn(r[4], r[5]), __fadd_rn(r[6], r[7])));
    }
    return __fadd_rn(__fadd_rn(blk[0], blk[1]), __fadd_rn(blk[2], blk[3]));
}

// ---------------- kernel 1: row sums of squares + sum|x| ----------------
__global__ void k_rowsums(const float* __restrict__ zE, const float* __restrict__ cb,
                          float* __restrict__ sq, float* __restrict__ e2,
                          float* __restrict__ sabs) {
    int row = blockIdx.x * 64 + threadIdx.x;          // 640 x 64 = 40960
    if (row < ROWS) {
        const float* p = zE + (size_t)row * D;
        sq[row] = np_sumsq_512(p);
        float sa = 0.0f;
#pragma unroll 8
        for (int k = 0; k < D; ++k) sa += fabsf(p[k]);
        sabs[row] = sa;
    } else {
        e2[row - ROWS] = np_sumsq_512(cb + (size_t)(row - ROWS) * D);
    }
}

// ---------------- kernel 2: f32 -> f16 conversion (cb scaled by 2^12) ----------------
__global__ void k_half(const float* __restrict__ zE, const float* __restrict__ cb,
                       _Float16* __restrict__ zh, _Float16* __restrict__ ch) {
    int i = (blockIdx.x * 256 + threadIdx.x) * 8;     // 10240 blocks
    if (i < ROWS * D) {
        float4 u = *(const float4*)(zE + i);
        float4 v = *(const float4*)(zE + i + 4);
        h8 o = {(_Float16)u.x, (_Float16)u.y, (_Float16)u.z, (_Float16)u.w,
                (_Float16)v.x, (_Float16)v.y, (_Float16)v.z, (_Float16)v.w};
        *(h8*)(zh + i) = o;
    } else {
        int j = i - ROWS * D;
        float4 u = *(const float4*)(cb + j);
        float4 v = *(const float4*)(cb + j + 4);
        h8 o = {(_Float16)(u.x * 4096.0f), (_Float16)(u.y * 4096.0f),
                (_Float16)(u.z * 4096.0f), (_Float16)(u.w * 4096.0f),
                (_Float16)(v.x * 4096.0f), (_Float16)(v.y * 4096.0f),
                (_Float16)(v.z * 4096.0f), (_Float16)(v.w * 4096.0f)};
        *(h8*)(ch + j) = o;
    }
}

// approx distance (deterministic)
__device__ __forceinline__ float dapprox(float s, float accv, float ecv) {
    float m = __fmul_rn(accv, 0.000244140625f);       // exact /4096
    return __fadd_rn(__fsub_rn(s, __fmul_rn(2.0f, m)), ecv);
}

// ---------------- kernel 3: fp16 MFMA distance pass -> per-tile minima ----------------
// Unchanged from round 13 (verified): tmin[row][tile] = min d~ over tile's 128 codes.
__global__ __launch_bounds__(256, 2)
void k_mfma_min(const _Float16* __restrict__ zh, const _Float16* __restrict__ ch,
                const float* __restrict__ sq, const float* __restrict__ e2,
                float* __restrict__ tmin) {
    const int p    = blockIdx.x;                      // 0..8191
    const int ct   = (p & 7) * 8 + ((p >> 3) & 7);    // code tile 0..63 (XCD-local)
    const int rt   = p >> 6;                          // row tile 0..127
    const int wave = threadIdx.x >> 6;
    const int lane = threadIdx.x & 63;
    const int l15  = lane & 15;
    const int lk   = lane >> 4;
    const int rw   = rt * 256 + wave * 64;
    const int cw   = ct * 128;

    f4v acc[4][8];
#pragma unroll
    for (int a = 0; a < 4; ++a)
#pragma unroll
        for (int b = 0; b < 8; ++b) acc[a][b] = (f4v){0.f, 0.f, 0.f, 0.f};

#pragma unroll 2
    for (int k0 = 0; k0 < D; k0 += 32) {
        h8 bf[8];
#pragma unroll
        for (int b = 0; b < 8; ++b)
            bf[b] = *(const h8*)(ch + (size_t)(cw + b * 16 + l15) * D + k0 + lk * 8);
#pragma unroll
        for (int a = 0; a < 4; ++a) {
            h8 af = *(const h8*)(zh + (size_t)(rw + a * 16 + l15) * D + k0 + lk * 8);
#pragma unroll
            for (int b = 0; b < 8; ++b)
                acc[a][b] = __builtin_amdgcn_mfma_f32_16x16x32_f16(af, bf[b], acc[a][b], 0, 0, 0);
        }
    }

#pragma unroll
    for (int a = 0; a < 4; ++a) {
        const int r0 = rw + a * 16 + lk * 4;
        float s0 = sq[r0 + 0], s1 = sq[r0 + 1], s2 = sq[r0 + 2], s3 = sq[r0 + 3];
        float rm[4] = {INFINITY, INFINITY, INFINITY, INFINITY};
#pragma unroll
        for (int b = 0; b < 8; ++b) {
            float ecv = e2[cw + b * 16 + l15];
            rm[0] = fminf(rm[0], dapprox(s0, acc[a][b][0], ecv));
            rm[1] = fminf(rm[1], dapprox(s1, acc[a][b][1], ecv));
            rm[2] = fminf(rm[2], dapprox(s2, acc[a][b][2], ecv));
            rm[3] = fminf(rm[3], dapprox(s3, acc[a][b][3], ecv));
        }
#pragma unroll
        for (int jj = 0; jj < 4; ++jj) {
            float v = rm[jj];
            v = fminf(v, __shfl_xor(v, 1));
            v = fminf(v, __shfl_xor(v, 2));
            v = fminf(v, __shfl_xor(v, 4));
            v = fminf(v, __shfl_xor(v, 8));
            if (l15 == 0) tmin[(size_t)(r0 + jj) * NTILES + ct] = v;
        }
    }
}

// ---------------- kernel 4: select tiles -> per-TILE row lists ----------------
__global__ void k_select(const float* __restrict__ tmin, const float* __restrict__ sabs,
                         int* __restrict__ tileCnt, int* __restrict__ tileRows,
                         unsigned long long* __restrict__ part64) {
    int row = blockIdx.x * 256 + threadIdx.x;
    if (row >= ROWS) return;
    part64[row] = 0xFFFFFFFFFFFFFFFFull;
    const float* t = tmin + (size_t)row * NTILES;
    float g = t[0];
#pragma unroll 8
    for (int i = 1; i < NTILES; ++i) g = fminf(g, t[i]);
    float thr = g + (sabs[row] * 8e-7f + 6e-4f);      // WIN = 2*err bound (verified)
    for (int i = 0; i < NTILES; ++i)
        if (t[i] <= thr) {
            int sl = atomicAdd(&tileCnt[i], 1);
            tileRows[(size_t)i * ROWS + sl] = row;    // capacity = ROWS, no overflow
        }
}

// ---------------- kernel 5: tile-major exact rescore ----------------
// One wave per (row, tile) pair; lane owns 2 codes; tile pinned to XCD t>>3 so
// its 256 KiB cb slice is L2-resident across all its rows. x-row reads are
// wave-uniform (L1 broadcast). Exact chain = verified dual-chain (asc k, split 384).
// Combine via atomicMin on pack=(d_bits<<32)|idx: lexicographic, order-independent.
__global__ __launch_bounds__(256)
void k_rescore(const float* __restrict__ zE, const float* __restrict__ cb,
               const float* __restrict__ sq, const float* __restrict__ e2,
               const int* __restrict__ tileCnt, const int* __restrict__ tileRows,
               unsigned long long* __restrict__ part64) {
    const int p     = blockIdx.x;                     // 0..8191
    const int t     = (p & 7) * 8 + ((p >> 3) & 7);   // tile, XCD-pinned (= mfma map)
    const int chunk = p >> 6;                         // 0..127
    const int wave  = threadIdx.x >> 6;
    const int lane  = threadIdx.x & 63;
    const int n     = tileCnt[t];

    for (int idx = chunk * 4 + wave; idx < n; idx += 512) {
        const int row = tileRows[(size_t)t * ROWS + idx];
        const float* xr = zE + (size_t)row * D;
        const float s = sq[row];
        float bd = INFINITY;
        int   bi = NCODES - 1;
#pragma unroll
        for (int h = 0; h < 2; ++h) {
            const int c = t * 128 + h * 64 + lane;
            const float* er = cb + (size_t)c * D;
            float m1 = 0.0f, m2 = 0.0f;
#pragma unroll 8
            for (int k = 0; k < KC; ++k) m1 = __builtin_fmaf(xr[k], er[k], m1);
#pragma unroll 8
            for (int k = KC; k < D; ++k) m2 = __builtin_fmaf(xr[k], er[k], m2);
            float m = __fadd_rn(m1, m2);
            float d = __fadd_rn(__fsub_rn(s, __fmul_rn(2.0f, m)), e2[c]);
            if (d < bd || (d == bd && c < bi)) { bd = d; bi = c; }
        }
#pragma unroll
        for (int off = 32; off; off >>= 1) {
            float v2 = __shfl_xor(bd, off);
            int   x2 = __shfl_xor(bi, off);
            if (v2 < bd || (v2 == bd && x2 < bi)) { bd = v2; bi = x2; }
        }
        if (lane == 0) {
            unsigned long long pack =
                ((unsigned long long)__float_as_uint(bd) << 32) | (unsigned)bi;
            atomicMin(&part64[row], pack);
        }
    }
}

// ---------------- kernel 6: unpack ids ----------------
__global__ void k_pick(const unsigned long long* __restrict__ part64,
                       int* __restrict__ ids, float* __restrict__ outIds) {
    int row = blockIdx.x * 256 + threadIdx.x;
    if (row >= ROWS) return;
    int bi = (int)(unsigned)(part64[row] & 0xFFFFFFFFull);
    bi = bi < 0 ? 0 : (bi > NCODES - 1 ? NCODES - 1 : bi);
    ids[row] = bi;
    outIds[row] = (float)bi;
}

// ---------------- kernel 7: gather z_q_st (f32) + loss partials (verified) ----------------
__global__ void k_gather(const float* __restrict__ zE, const float* __restrict__ cb,
                         const int* __restrict__ ids, float* __restrict__ outZ,
                         double* __restrict__ lossPart) {
    const int tid = threadIdx.x;
    double acc = 0.0;
#pragma unroll
    for (int it = 0; it < 4; ++it) {
        int chunk = blockIdx.x * 256 + tid + it * 1048576;
        int row   = chunk >> 7;
        int koff  = (chunk & 127) << 2;
        int id    = ids[row];
        id = id < 0 ? 0 : (id > NCODES - 1 ? NCODES - 1 : id);
        float4 ze = *(const float4*)(zE + ((size_t)row << 9) + koff);
        float4 zq = *(const float4*)(cb + ((size_t)id << 9) + koff);
        float d0 = __fsub_rn(zq.x, ze.x);
        float d1 = __fsub_rn(zq.y, ze.y);
        float d2 = __fsub_rn(zq.z, ze.z);
        float d3 = __fsub_rn(zq.w, ze.w);
        float4 v;
        v.x = __fadd_rn(ze.x, d0);
        v.y = __fadd_rn(ze.y, d1);
        v.z = __fadd_rn(ze.z, d2);
        v.w = __fadd_rn(ze.w, d3);
        *reinterpret_cast<float4*>(outZ + ((size_t)chunk << 2)) = v;
        acc += (double)d0 * d0 + (double)d1 * d1 + (double)d2 * d2 + (double)d3 * d3;
    }
    for (int off = 32; off; off >>= 1) acc += __shfl_down(acc, off);
    __shared__ double sred[4];
    if ((tid & 63) == 0) sred[tid >> 6] = acc;
    __syncthreads();
    if (tid == 0) lossPart[blockIdx.x] = (sred[0] + sred[1]) + (sred[2] + sred[3]);
}

// ---------------- kernel 8: final loss (verified) ----------------
__global__ void k_loss(const double* __restrict__ lossPart, float* __restrict__ outLoss) {
    const int tid = threadIdx.x;
    double acc = 0.0;
    for (int i = tid; i < 4096; i += 256) acc += lossPart[i];
    for (int off = 32; off; off >>= 1) acc += __shfl_down(acc, off);
    __shared__ double sred[4];
    if ((tid & 63) == 0) sred[tid >> 6] = acc;
    __syncthreads();
    if (tid == 0) {
        double mean = ((sred[0] + sred[1]) + (sred[2] + sred[3])) / 16777216.0;
        float cl = (float)mean;
        *outLoss = __fadd_rn(cl, __fmul_rn(0.25f, cl));
    }
}

extern "C" void kernel_launch(void* const* d_in, const int* in_sizes, int n_in,
                              void* d_out, int out_size, void* d_ws, size_t ws_size,
                              hipStream_t stream) {
    (void)in_sizes; (void)n_in; (void)out_size; (void)ws_size;
    const float* zE = (const float*)d_in[0];
    const float* cb = (const float*)d_in[1];
    float* out = (float*)d_out;
    char*  ws  = (char*)d_ws;
    char*  ob  = (char*)d_out;

    // ws scratch (small, same 1.4 MiB envelope as rounds 4-13)
    float*              sq       = (float*)(ws + 0);          // 128 KiB
    float*              e2       = (float*)(ws + 131072);     // 32 KiB
    int*                ids      = (int*)(ws + 163840);       // 128 KiB
    float*              sabs     = (float*)(ws + 294912);     // 128 KiB
    int*                tileCnt  = (int*)(ws + 425984);       // 256 B
    unsigned long long* part64   = (unsigned long long*)(ws + 430080); // 256 KiB
    double*             lossPart = (double*)(ws + 1343488);   // 32 KiB

    // big scratch inside d_out region 0 (fully overwritten by k_gather afterwards)
    _Float16* zh       = (_Float16*)(ob + 0);            // 32 MiB
    _Float16* ch       = (_Float16*)(ob + 33554432);     //  8 MiB
    float*    tmin     = (float*)(ob + 41943040);        //  8 MiB
    int*      tileRows = (int*)(ob + 50331648);          //  8 MiB (64 x 32768)

    k_rowsums<<<(ROWS + NCODES) / 64, 64, 0, stream>>>(zE, cb, sq, e2, sabs);
    k_half<<<(ROWS + NCODES) * (D / 8) / 256, 256, 0, stream>>>(zE, cb, zh, ch);
    k_mfma_min<<<8192, 256, 0, stream>>>(zh, ch, sq, e2, tmin);
    hipMemsetAsync(tileCnt, 0, 256, stream);
    k_select<<<ROWS / 256, 256, 0, stream>>>(tmin, sabs, tileCnt, tileRows, part64);
    k_rescore<<<8192, 256, 0, stream>>>(zE, cb, sq, e2, tileCnt, tileRows, part64);
    k_pick<<<ROWS / 256, 256, 0, stream>>>(part64, ids, out + 16777216);
    k_gather<<<4096, 256, 0, stream>>>(zE, cb, ids, out, lossPart);
    k_loss<<<1, 256, 0, stream>>>(lossPart, out + 16777216 + 32768);
}

// Round 15
// 1563.898 us; speedup vs baseline: 4.0239x; 2.9560x over previous
//
#include <hip/hip_runtime.h>

#define ROWS 32768      // B*T
#define D 512
#define NCODES 8192
#define KC 384          // OpenBLAS sgemm kc panel split (verified exact, rounds 4-14)
#define NTILES 64       // 8192 codes / 128
#define NSLOT 64

typedef _Float16 h8 __attribute__((ext_vector_type(8)));
typedef float f4v __attribute__((ext_vector_type(4)));

// numpy pairwise f32 sum of squares of a 512-float row (verified exact).
__device__ __forceinline__ float np_sumsq_512(const float* __restrict__ p) {
    float blk[4];
#pragma unroll
    for (int b = 0; b < 4; ++b) {
        const float* q = p + b * 128;
        float r[8];
#pragma unroll
        for (int j = 0; j < 8; ++j) r[j] = __fmul_rn(q[j], q[j]);
#pragma unroll
        for (int i = 1; i < 16; ++i)
#pragma unroll
            for (int j = 0; j < 8; ++j)
                r[j] = __fadd_rn(r[j], __fmul_rn(q[i * 8 + j], q[i * 8 + j]));
        blk[b] = __fadd_rn(__fadd_rn(__fadd_rn(r[0], r[1]), __fadd_rn(r[2], r[3])),
                           __fadd_rn(__fadd_rn(r[4], r[5]), __fadd_rn(r[6], r[7])));
    }
    return __fadd_rn(__fadd_rn(blk[0], blk[1]), __fadd_rn(blk[2], blk[3]));
}

// ---------------- kernel 1: row sums of squares + sum|x| ----------------
__global__ void k_rowsums(const float* __restrict__ zE, const float* __restrict__ cb,
                          float* __restrict__ sq, float* __restrict__ e2,
                          float* __restrict__ sabs) {
    int row = blockIdx.x * 64 + threadIdx.x;
    if (row < ROWS) {
        const float* p = zE + (size_t)row * D;
        sq[row] = np_sumsq_512(p);
        float sa = 0.0f;
#pragma unroll 8
        for (int k = 0; k < D; ++k) sa += fabsf(p[k]);
        sabs[row] = sa;
    } else {
        e2[row - ROWS] = np_sumsq_512(cb + (size_t)(row - ROWS) * D);
    }
}

// ---------------- kernel 2: f32 -> f16 conversion (cb scaled by 2^12) ----------------
__global__ void k_half(const float* __restrict__ zE, const float* __restrict__ cb,
                       _Float16* __restrict__ zh, _Float16* __restrict__ ch) {
    int i = (blockIdx.x * 256 + threadIdx.x) * 8;
    if (i < ROWS * D) {
        float4 u = *(const float4*)(zE + i);
        float4 v = *(const float4*)(zE + i + 4);
        h8 o = {(_Float16)u.x, (_Float16)u.y, (_Float16)u.z, (_Float16)u.w,
                (_Float16)v.x, (_Float16)v.y, (_Float16)v.z, (_Float16)v.w};
        *(h8*)(zh + i) = o;
    } else {
        int j = i - ROWS * D;
        float4 u = *(const float4*)(cb + j);
        float4 v = *(const float4*)(cb + j + 4);
        h8 o = {(_Float16)(u.x * 4096.0f), (_Float16)(u.y * 4096.0f),
                (_Float16)(u.z * 4096.0f), (_Float16)(u.w * 4096.0f),
                (_Float16)(v.x * 4096.0f), (_Float16)(v.y * 4096.0f),
                (_Float16)(v.z * 4096.0f), (_Float16)(v.w * 4096.0f)};
        *(h8*)(ch + j) = o;
    }
}

// approx distance (deterministic; identical in both MFMA kernels)
__device__ __forceinline__ float dapprox(float s, float accv, float ecv) {
    float m = __fmul_rn(accv, 0.000244140625f);       // exact /4096
    return __fadd_rn(__fsub_rn(s, __fmul_rn(2.0f, m)), ecv);
}

// ---------------- kernel 3: fp16 MFMA pass 1 -> per-tile minima ----------------
__global__ __launch_bounds__(256, 2)
void k_mfma_min(const _Float16* __restrict__ zh, const _Float16* __restrict__ ch,
                const float* __restrict__ sq, const float* __restrict__ e2,
                float* __restrict__ tmin) {
    const int p    = blockIdx.x;                      // 0..8191
    const int ct   = (p & 7) * 8 + ((p >> 3) & 7);    // code tile 0..63 (XCD-local)
    const int rt   = p >> 6;                          // row tile 0..127
    const int wave = threadIdx.x >> 6;
    const int lane = threadIdx.x & 63;
    const int l15  = lane & 15;
    const int lk   = lane >> 4;
    const int rw   = rt * 256 + wave * 64;
    const int cw   = ct * 128;

    f4v acc[4][8];
#pragma unroll
    for (int a = 0; a < 4; ++a)
#pragma unroll
        for (int b = 0; b < 8; ++b) acc[a][b] = (f4v){0.f, 0.f, 0.f, 0.f};

#pragma unroll 2
    for (int k0 = 0; k0 < D; k0 += 32) {
        h8 bf[8];
#pragma unroll
        for (int b = 0; b < 8; ++b)
            bf[b] = *(const h8*)(ch + (size_t)(cw + b * 16 + l15) * D + k0 + lk * 8);
#pragma unroll
        for (int a = 0; a < 4; ++a) {
            h8 af = *(const h8*)(zh + (size_t)(rw + a * 16 + l15) * D + k0 + lk * 8);
#pragma unroll
            for (int b = 0; b < 8; ++b)
                acc[a][b] = __builtin_amdgcn_mfma_f32_16x16x32_f16(af, bf[b], acc[a][b], 0, 0, 0);
        }
    }

#pragma unroll
    for (int a = 0; a < 4; ++a) {
        const int r0 = rw + a * 16 + lk * 4;
        float s0 = sq[r0 + 0], s1 = sq[r0 + 1], s2 = sq[r0 + 2], s3 = sq[r0 + 3];
        float rm[4] = {INFINITY, INFINITY, INFINITY, INFINITY};
#pragma unroll
        for (int b = 0; b < 8; ++b) {
            float ecv = e2[cw + b * 16 + l15];
            rm[0] = fminf(rm[0], dapprox(s0, acc[a][b][0], ecv));
            rm[1] = fminf(rm[1], dapprox(s1, acc[a][b][1], ecv));
            rm[2] = fminf(rm[2], dapprox(s2, acc[a][b][2], ecv));
            rm[3] = fminf(rm[3], dapprox(s3, acc[a][b][3], ecv));
        }
#pragma unroll
        for (int jj = 0; jj < 4; ++jj) {
            float v = rm[jj];
            v = fminf(v, __shfl_xor(v, 1));
            v = fminf(v, __shfl_xor(v, 2));
            v = fminf(v, __shfl_xor(v, 4));
            v = fminf(v, __shfl_xor(v, 8));
            if (l15 == 0) tmin[(size_t)(r0 + jj) * NTILES + ct] = v;
        }
    }
}

// ---------------- kernel 4: per-row threshold + per-tile row lists ----------------
__global__ void k_select(const float* __restrict__ tmin, const float* __restrict__ sabs,
                         float* __restrict__ thr, int* __restrict__ tileCnt,
                         int* __restrict__ tileRows) {
    int row = blockIdx.x * 256 + threadIdx.x;
    if (row >= ROWS) return;
    const float* t = tmin + (size_t)row * NTILES;
    float g = t[0];
#pragma unroll 8
    for (int i = 1; i < NTILES; ++i) g = fminf(g, t[i]);
    float th = g + (sabs[row] * 8e-7f + 6e-4f);       // WIN = 2*err bound (verified)
    thr[row] = th;
    for (int i = 0; i < NTILES; ++i)
        if (t[i] <= th) {
            int sl = atomicAdd(&tileCnt[i], 1);
            tileRows[(size_t)i * ROWS + sl] = row;
        }
}

// ---------------- kernel 5: fp16 MFMA pass 2 (qualifying pairs only) -> candidates ----
// Tile-major; rows gathered from tileRows in groups of 64. k-loop/MFMA sequence
// IDENTICAL to pass 1 -> d~ bit-identical per (row,code). Collect d~ <= thr[row].
__global__ __launch_bounds__(256, 2)
void k_mfma_cand(const _Float16* __restrict__ zh, const _Float16* __restrict__ ch,
                 const float* __restrict__ sq, const float* __restrict__ e2,
                 const float* __restrict__ thr, const int* __restrict__ tileCnt,
                 const int* __restrict__ tileRows, int* __restrict__ cnt,
                 int* __restrict__ cands) {
    const int p     = blockIdx.x;                     // 0..255
    const int t     = (p & 7) * 8 + ((p >> 3) & 7);   // tile, XCD-pinned (= pass-1 map)
    const int chunk = p >> 6;                         // 0..3
    const int wave  = threadIdx.x >> 6;
    const int lane  = threadIdx.x & 63;
    const int l15   = lane & 15;
    const int lk    = lane >> 4;
    const int cw    = t * 128;
    const int n     = tileCnt[t];
    const int ngrp  = (n + 63) >> 6;

    for (int g = chunk * 4 + wave; g < ngrp; g += 16) {
        int gi = g * 64 + lane;
        int myrow = (gi < n) ? tileRows[(size_t)t * ROWS + gi] : -1;

        f4v acc[4][8];
#pragma unroll
        for (int a = 0; a < 4; ++a)
#pragma unroll
            for (int b = 0; b < 8; ++b) acc[a][b] = (f4v){0.f, 0.f, 0.f, 0.f};

#pragma unroll 2
        for (int k0 = 0; k0 < D; k0 += 32) {
            h8 bf[8];
#pragma unroll
            for (int b = 0; b < 8; ++b)
                bf[b] = *(const h8*)(ch + (size_t)(cw + b * 16 + l15) * D + k0 + lk * 8);
#pragma unroll
            for (int a = 0; a < 4; ++a) {
                int ra = __shfl(myrow, a * 16 + l15);
                ra = ra < 0 ? 0 : ra;
                h8 af = *(const h8*)(zh + (size_t)ra * D + k0 + lk * 8);
#pragma unroll
                for (int b = 0; b < 8; ++b)
                    acc[a][b] = __builtin_amdgcn_mfma_f32_16x16x32_f16(af, bf[b], acc[a][b], 0, 0, 0);
            }
        }

#pragma unroll
        for (int a = 0; a < 4; ++a) {
#pragma unroll
            for (int jj = 0; jj < 4; ++jj) {
                int rowv = __shfl(myrow, a * 16 + lk * 4 + jj);
                if (rowv < 0) continue;
                float s  = sq[rowv];
                float th = thr[rowv];
#pragma unroll
                for (int b = 0; b < 8; ++b) {
                    int c = cw + b * 16 + l15;
                    float d = dapprox(s, acc[a][b][jj], e2[c]);
                    if (d <= th) {
                        int sl = atomicAdd(&cnt[rowv], 1);
                        if (sl < NSLOT) cands[(size_t)rowv * NSLOT + sl] = c;
                    }
                }
            }
        }
    }
}

// exact distance: verified dual-chain, sequential ascending-k FMA
__device__ __forceinline__ float exact_d(const float* __restrict__ xr,
                                         const float* __restrict__ er,
                                         float s, float ev) {
    float m1 = 0.0f, m2 = 0.0f;
#pragma unroll 8
    for (int k = 0; k < KC; ++k) m1 = __builtin_fmaf(xr[k], er[k], m1);
#pragma unroll 8
    for (int k = KC; k < D; ++k) m2 = __builtin_fmaf(xr[k], er[k], m2);
    float m = __fadd_rn(m1, m2);
    return __fadd_rn(__fsub_rn(s, __fmul_rn(2.0f, m)), ev);
}

// ---------------- kernel 6: exact rescore of candidates -> ids (r12 shape) --------
__global__ void k_rescore(const float* __restrict__ zE, const float* __restrict__ cb,
                          const float* __restrict__ sq, const float* __restrict__ e2,
                          const int* __restrict__ cnt, const int* __restrict__ cands,
                          int* __restrict__ ids, float* __restrict__ outIds) {
    int row = blockIdx.x * 256 + threadIdx.x;
    if (row >= ROWS) return;
    const float* xr = zE + (size_t)row * D;
    float s = sq[row];
    int   n = cnt[row];
    float bd = INFINITY;
    int   bi = NCODES - 1;
    if (n <= NSLOT) {
        for (int t = 0; t < n; ++t) {
            int c = cands[(size_t)row * NSLOT + t];
            float d = exact_d(xr, cb + (size_t)c * D, s, e2[c]);
            if (d < bd || (d == bd && c < bi)) { bd = d; bi = c; }
        }
    } else {                                          // sound fallback (never expected)
        for (int c = 0; c < NCODES; ++c) {
            float d = exact_d(xr, cb + (size_t)c * D, s, e2[c]);
            if (d < bd) { bd = d; bi = c; }
        }
    }
    bi = bi < 0 ? 0 : (bi > NCODES - 1 ? NCODES - 1 : bi);
    ids[row] = bi;
    outIds[row] = (float)bi;
}

// ---------------- kernel 7: gather z_q_st (f32) + loss partials (verified) --------
__global__ void k_gather(const float* __restrict__ zE, const float* __restrict__ cb,
                         const int* __restrict__ ids, float* __restrict__ outZ,
                         double* __restrict__ lossPart) {
    const int tid = threadIdx.x;
    double acc = 0.0;
#pragma unroll
    for (int it = 0; it < 4; ++it) {
        int chunk = blockIdx.x * 256 + tid + it * 1048576;
        int row   = chunk >> 7;
        int koff  = (chunk & 127) << 2;
        int id    = ids[row];
        id = id < 0 ? 0 : (id > NCODES - 1 ? NCODES - 1 : id);
        float4 ze = *(const float4*)(zE + ((size_t)row << 9) + koff);
        float4 zq = *(const float4*)(cb + ((size_t)id << 9) + koff);
        float d0 = __fsub_rn(zq.x, ze.x);
        float d1 = __fsub_rn(zq.y, ze.y);
        float d2 = __fsub_rn(zq.z, ze.z);
        float d3 = __fsub_rn(zq.w, ze.w);
        float4 v;
        v.x = __fadd_rn(ze.x, d0);
        v.y = __fadd_rn(ze.y, d1);
        v.z = __fadd_rn(ze.z, d2);
        v.w = __fadd_rn(ze.w, d3);
        *reinterpret_cast<float4*>(outZ + ((size_t)chunk << 2)) = v;
        acc += (double)d0 * d0 + (double)d1 * d1 + (double)d2 * d2 + (double)d3 * d3;
    }
    for (int off = 32; off; off >>= 1) acc += __shfl_down(acc, off);
    __shared__ double sred[4];
    if ((tid & 63) == 0) sred[tid >> 6] = acc;
    __syncthreads();
    if (tid == 0) lossPart[blockIdx.x] = (sred[0] + sred[1]) + (sred[2] + sred[3]);
}

// ---------------- kernel 8: final loss (verified) ----------------
__global__ void k_loss(const double* __restrict__ lossPart, float* __restrict__ outLoss) {
    const int tid = threadIdx.x;
    double acc = 0.0;
    for (int i = tid; i < 4096; i += 256) acc += lossPart[i];
    for (int off = 32; off; off >>= 1) acc += __shfl_down(acc, off);
    __shared__ double sred[4];
    if ((tid & 63) == 0) sred[tid >> 6] = acc;
    __syncthreads();
    if (tid == 0) {
        double mean = ((sred[0] + sred[1]) + (sred[2] + sred[3])) / 16777216.0;
        float cl = (float)mean;
        *outLoss = __fadd_rn(cl, __fmul_rn(0.25f, cl));
    }
}

extern "C" void kernel_launch(void* const* d_in, const int* in_sizes, int n_in,
                              void* d_out, int out_size, void* d_ws, size_t ws_size,
                              hipStream_t stream) {
    (void)in_sizes; (void)n_in; (void)out_size; (void)ws_size;
    const float* zE = (const float*)d_in[0];
    const float* cb = (const float*)d_in[1];
    float* out = (float*)d_out;
    char*  ws  = (char*)d_ws;
    char*  ob  = (char*)d_out;

    // ws scratch (small, same envelope as rounds 4-14)
    float*  sq       = (float*)(ws + 0);              // 128 KiB
    float*  e2       = (float*)(ws + 131072);         // 32 KiB
    int*    ids      = (int*)(ws + 163840);           // 128 KiB
    float*  sabs     = (float*)(ws + 294912);         // 128 KiB
    int*    tileCnt  = (int*)(ws + 425984);           // 256 B
    float*  thr      = (float*)(ws + 430080);         // 128 KiB
    int*    cnt      = (int*)(ws + 561152);           // 128 KiB
    double* lossPart = (double*)(ws + 1343488);       // 32 KiB

    // big scratch inside d_out region 0 (fully overwritten by k_gather afterwards)
    _Float16* zh       = (_Float16*)(ob + 0);            // 32 MiB
    _Float16* ch       = (_Float16*)(ob + 33554432);     //  8 MiB
    float*    tmin     = (float*)(ob + 41943040);        //  8 MiB
    int*      tileRows = (int*)(ob + 50331648);          //  8 MiB
    int*      cands    = (int*)(ob + 58720256);          //  8 MiB (32768 x 64)

    k_rowsums<<<(ROWS + NCODES) / 64, 64, 0, stream>>>(zE, cb, sq, e2, sabs);
    k_half<<<(ROWS + NCODES) * (D / 8) / 256, 256, 0, stream>>>(zE, cb, zh, ch);
    k_mfma_min<<<8192, 256, 0, stream>>>(zh, ch, sq, e2, tmin);
    hipMemsetAsync(tileCnt, 0, 256, stream);
    hipMemsetAsync(cnt, 0, 131072, stream);
    k_select<<<ROWS / 256, 256, 0, stream>>>(tmin, sabs, thr, tileCnt, tileRows);
    k_mfma_cand<<<256, 256, 0, stream>>>(zh, ch, sq, e2, thr, tileCnt, tileRows,
                                         cnt, cands);
    k_rescore<<<ROWS / 256, 256, 0, stream>>>(zE, cb, sq, e2, cnt, cands,
                                              ids, out + 16777216);
    k_gather<<<4096, 256, 0, stream>>>(zE, cb, ids, out, lossPart);
    k_loss<<<1, 256, 0, stream>>>(lossPart, out + 16777216 + 32768);
}

// Round 16
// 1393.068 us; speedup vs baseline: 4.5174x; 1.1226x over previous
//
#include <hip/hip_runtime.h>

#define ROWS 32768      // B*T
#define D 512
#define NCODES 8192
#define KC 384          // OpenBLAS sgemm kc panel split (verified exact, rounds 4-15)
#define NTILES 64       // 8192 codes / 128
#define NSLOT 64

typedef _Float16 h8 __attribute__((ext_vector_type(8)));
typedef float f4v __attribute__((ext_vector_type(4)));

// ---------------- kernel 1: row sums (wave-per-row, np-pairwise-exact) ----------------
// Lanes 0..31: numpy's 32 chains (b=lane>>3 block of 128, j=lane&7 stride-8 chain),
// each sequential over i=0..15. Merge tree == shfl_xor 1,2,4 (within-block) then
// 8,16 (block merge) with __fadd_rn (RN add commutative -> both pair lanes equal).
// Lanes 32..63: sum|x| partials (feeds the WIN margin only; deterministic).
__global__ __launch_bounds__(256)
void k_rowsums(const float* __restrict__ zE, const float* __restrict__ cb,
               float* __restrict__ sq, float* __restrict__ e2,
               float* __restrict__ sabs) {
    const int wid  = blockIdx.x * 4 + (threadIdx.x >> 6);   // 0..40959
    const int lane = threadIdx.x & 63;
    const float* p = (wid < ROWS) ? zE + (size_t)wid * D
                                  : cb + (size_t)(wid - ROWS) * D;
    float v;
    if (lane < 32) {
        const int b = lane >> 3, j = lane & 7;
        const float* q = p + b * 128 + j;
        float r = __fmul_rn(q[0], q[0]);
#pragma unroll
        for (int i = 1; i < 16; ++i) {
            float t = q[i * 8];
            r = __fadd_rn(r, __fmul_rn(t, t));
        }
        v = r;
    } else {
        const int m = lane - 32;
        float sa = 0.0f;
#pragma unroll
        for (int i = 0; i < 16; ++i) sa += fabsf(p[i * 32 + m]);
        v = sa;
    }
    v = __fadd_rn(v, __shfl_xor(v, 1));
    v = __fadd_rn(v, __shfl_xor(v, 2));
    v = __fadd_rn(v, __shfl_xor(v, 4));
    v = __fadd_rn(v, __shfl_xor(v, 8));
    v = __fadd_rn(v, __shfl_xor(v, 16));
    float sa = __shfl(v, 32);
    if (lane == 0) {
        if (wid < ROWS) { sq[wid] = v; sabs[wid] = sa; }
        else            { e2[wid - ROWS] = v; }
    }
}

// ---------------- kernel 2: f32 -> f16 conversion (cb scaled by 2^12) ----------------
__global__ void k_half(const float* __restrict__ zE, const float* __restrict__ cb,
                       _Float16* __restrict__ zh, _Float16* __restrict__ ch) {
    int i = (blockIdx.x * 256 + threadIdx.x) * 8;
    if (i < ROWS * D) {
        float4 u = *(const float4*)(zE + i);
        float4 v = *(const float4*)(zE + i + 4);
        h8 o = {(_Float16)u.x, (_Float16)u.y, (_Float16)u.z, (_Float16)u.w,
                (_Float16)v.x, (_Float16)v.y, (_Float16)v.z, (_Float16)v.w};
        *(h8*)(zh + i) = o;
    } else {
        int j = i - ROWS * D;
        float4 u = *(const float4*)(cb + j);
        float4 v = *(const float4*)(cb + j + 4);
        h8 o = {(_Float16)(u.x * 4096.0f), (_Float16)(u.y * 4096.0f),
                (_Float16)(u.z * 4096.0f), (_Float16)(u.w * 4096.0f),
                (_Float16)(v.x * 4096.0f), (_Float16)(v.y * 4096.0f),
                (_Float16)(v.z * 4096.0f), (_Float16)(v.w * 4096.0f)};
        *(h8*)(ch + j) = o;
    }
}

// approx distance (deterministic; identical in both MFMA kernels)
__device__ __forceinline__ float dapprox(float s, float accv, float ecv) {
    float m = __fmul_rn(accv, 0.000244140625f);       // exact /4096
    return __fadd_rn(__fsub_rn(s, __fmul_rn(2.0f, m)), ecv);
}

// ---------------- kernel 3: fp16 MFMA pass 1 -> per-tile minima ----------------
// tmin now TRANSPOSED: tmin[tile][row] so k_select reads coalesce.
__global__ __launch_bounds__(256, 2)
void k_mfma_min(const _Float16* __restrict__ zh, const _Float16* __restrict__ ch,
                const float* __restrict__ sq, const float* __restrict__ e2,
                float* __restrict__ tmin) {
    const int p    = blockIdx.x;                      // 0..8191
    const int ct   = (p & 7) * 8 + ((p >> 3) & 7);    // code tile 0..63 (XCD-local)
    const int rt   = p >> 6;                          // row tile 0..127
    const int wave = threadIdx.x >> 6;
    const int lane = threadIdx.x & 63;
    const int l15  = lane & 15;
    const int lk   = lane >> 4;
    const int rw   = rt * 256 + wave * 64;
    const int cw   = ct * 128;

    f4v acc[4][8];
#pragma unroll
    for (int a = 0; a < 4; ++a)
#pragma unroll
        for (int b = 0; b < 8; ++b) acc[a][b] = (f4v){0.f, 0.f, 0.f, 0.f};

#pragma unroll 2
    for (int k0 = 0; k0 < D; k0 += 32) {
        h8 bf[8];
#pragma unroll
        for (int b = 0; b < 8; ++b)
            bf[b] = *(const h8*)(ch + (size_t)(cw + b * 16 + l15) * D + k0 + lk * 8);
#pragma unroll
        for (int a = 0; a < 4; ++a) {
            h8 af = *(const h8*)(zh + (size_t)(rw + a * 16 + l15) * D + k0 + lk * 8);
#pragma unroll
            for (int b = 0; b < 8; ++b)
                acc[a][b] = __builtin_amdgcn_mfma_f32_16x16x32_f16(af, bf[b], acc[a][b], 0, 0, 0);
        }
    }

#pragma unroll
    for (int a = 0; a < 4; ++a) {
        const int r0 = rw + a * 16 + lk * 4;
        float s0 = sq[r0 + 0], s1 = sq[r0 + 1], s2 = sq[r0 + 2], s3 = sq[r0 + 3];
        float rm[4] = {INFINITY, INFINITY, INFINITY, INFINITY};
#pragma unroll
        for (int b = 0; b < 8; ++b) {
            float ecv = e2[cw + b * 16 + l15];
            rm[0] = fminf(rm[0], dapprox(s0, acc[a][b][0], ecv));
            rm[1] = fminf(rm[1], dapprox(s1, acc[a][b][1], ecv));
            rm[2] = fminf(rm[2], dapprox(s2, acc[a][b][2], ecv));
            rm[3] = fminf(rm[3], dapprox(s3, acc[a][b][3], ecv));
        }
#pragma unroll
        for (int jj = 0; jj < 4; ++jj) {
            float v = rm[jj];
            v = fminf(v, __shfl_xor(v, 1));
            v = fminf(v, __shfl_xor(v, 2));
            v = fminf(v, __shfl_xor(v, 4));
            v = fminf(v, __shfl_xor(v, 8));
            if (l15 == 0) tmin[(size_t)ct * ROWS + (r0 + jj)] = v;   // [tile][row]
        }
    }
}

// ---------------- kernel 4: per-row threshold + per-tile row lists ----------------
__global__ void k_select(const float* __restrict__ tmin, const float* __restrict__ sabs,
                         float* __restrict__ thr, int* __restrict__ tileCnt,
                         int* __restrict__ tileRows) {
    int row = blockIdx.x * 256 + threadIdx.x;
    if (row >= ROWS) return;
    float g = tmin[row];                              // tile 0
#pragma unroll 8
    for (int i = 1; i < NTILES; ++i) g = fminf(g, tmin[(size_t)i * ROWS + row]);
    float th = g + (sabs[row] * 8e-7f + 6e-4f);       // WIN = 2*err bound (verified)
    thr[row] = th;
    for (int i = 0; i < NTILES; ++i)
        if (tmin[(size_t)i * ROWS + row] <= th) {
            int sl = atomicAdd(&tileCnt[i], 1);
            tileRows[(size_t)i * ROWS + sl] = row;
        }
}

// ---------------- kernel 5: fp16 MFMA pass 2 (qualifying pairs only) -> candidates ----
__global__ __launch_bounds__(256, 2)
void k_mfma_cand(const _Float16* __restrict__ zh, const _Float16* __restrict__ ch,
                 const float* __restrict__ sq, const float* __restrict__ e2,
                 const float* __restrict__ thr, const int* __restrict__ tileCnt,
                 const int* __restrict__ tileRows, int* __restrict__ cnt,
                 int* __restrict__ cands) {
    const int p     = blockIdx.x;                     // 0..255
    const int t     = (p & 7) * 8 + ((p >> 3) & 7);   // tile, XCD-pinned (= pass-1 map)
    const int chunk = p >> 6;                         // 0..3
    const int wave  = threadIdx.x >> 6;
    const int lane  = threadIdx.x & 63;
    const int l15   = lane & 15;
    const int lk    = lane >> 4;
    const int cw    = t * 128;
    const int n     = tileCnt[t];
    const int ngrp  = (n + 63) >> 6;

    for (int g = chunk * 4 + wave; g < ngrp; g += 16) {
        int gi = g * 64 + lane;
        int myrow = (gi < n) ? tileRows[(size_t)t * ROWS + gi] : -1;

        f4v acc[4][8];
#pragma unroll
        for (int a = 0; a < 4; ++a)
#pragma unroll
            for (int b = 0; b < 8; ++b) acc[a][b] = (f4v){0.f, 0.f, 0.f, 0.f};

#pragma unroll 2
        for (int k0 = 0; k0 < D; k0 += 32) {
            h8 bf[8];
#pragma unroll
            for (int b = 0; b < 8; ++b)
                bf[b] = *(const h8*)(ch + (size_t)(cw + b * 16 + l15) * D + k0 + lk * 8);
#pragma unroll
            for (int a = 0; a < 4; ++a) {
                int ra = __shfl(myrow, a * 16 + l15);
                ra = ra < 0 ? 0 : ra;
                h8 af = *(const h8*)(zh + (size_t)ra * D + k0 + lk * 8);
#pragma unroll
                for (int b = 0; b < 8; ++b)
                    acc[a][b] = __builtin_amdgcn_mfma_f32_16x16x32_f16(af, bf[b], acc[a][b], 0, 0, 0);
            }
        }

#pragma unroll
        for (int a = 0; a < 4; ++a) {
#pragma unroll
            for (int jj = 0; jj < 4; ++jj) {
                int rowv = __shfl(myrow, a * 16 + lk * 4 + jj);
                if (rowv < 0) continue;
                float s  = sq[rowv];
                float th = thr[rowv];
#pragma unroll
                for (int b = 0; b < 8; ++b) {
                    int c = cw + b * 16 + l15;
                    float d = dapprox(s, acc[a][b][jj], e2[c]);
                    if (d <= th) {
                        int sl = atomicAdd(&cnt[rowv], 1);
                        if (sl < NSLOT) cands[(size_t)rowv * NSLOT + sl] = c;
                    }
                }
            }
        }
    }
}

// exact distance: verified dual-chain, sequential ascending-k FMA
__device__ __forceinline__ float exact_d(const float* __restrict__ xr,
                                         const float* __restrict__ er,
                                         float s, float ev) {
    float m1 = 0.0f, m2 = 0.0f;
#pragma unroll 8
    for (int k = 0; k < KC; ++k) m1 = __builtin_fmaf(xr[k], er[k], m1);
#pragma unroll 8
    for (int k = KC; k < D; ++k) m2 = __builtin_fmaf(xr[k], er[k], m2);
    float m = __fadd_rn(m1, m2);
    return __fadd_rn(__fsub_rn(s, __fmul_rn(2.0f, m)), ev);
}

// ---------------- kernel 6: exact rescore (wave-per-row, LDS-staged x) ----------------
__global__ __launch_bounds__(256)
void k_rescore(const float* __restrict__ zE, const float* __restrict__ cb,
               const float* __restrict__ sq, const float* __restrict__ e2,
               const int* __restrict__ cnt, const int* __restrict__ cands,
               int* __restrict__ ids, float* __restrict__ outIds) {
    __shared__ float xs[4][D];
    const int wave = threadIdx.x >> 6;
    const int lane = threadIdx.x & 63;
    const int row  = blockIdx.x * 4 + wave;

    const float* xr = zE + (size_t)row * D;
    *(float4*)&xs[wave][lane * 8]     = *(const float4*)(xr + lane * 8);
    *(float4*)&xs[wave][lane * 8 + 4] = *(const float4*)(xr + lane * 8 + 4);
    __syncthreads();

    float s = sq[row];
    int   n = cnt[row];
    float bd = INFINITY;
    int   bi = NCODES - 1;
    if (n <= NSLOT) {
        for (int t = lane; t < n; t += 64) {
            int c = cands[(size_t)row * NSLOT + t];
            float d = exact_d(xs[wave], cb + (size_t)c * D, s, e2[c]);
            if (d < bd || (d == bd && c < bi)) { bd = d; bi = c; }
        }
    } else {                                          // sound fallback (never expected)
        for (int c = lane; c < NCODES; c += 64) {     // ascending per lane
            float d = exact_d(xs[wave], cb + (size_t)c * D, s, e2[c]);
            if (d < bd || (d == bd && c < bi)) { bd = d; bi = c; }
        }
    }
#pragma unroll
    for (int off = 32; off; off >>= 1) {
        float v2 = __shfl_xor(bd, off);
        int   x2 = __shfl_xor(bi, off);
        if (v2 < bd || (v2 == bd && x2 < bi)) { bd = v2; bi = x2; }
    }
    if (lane == 0) {
        int b = bi < 0 ? 0 : (bi > NCODES - 1 ? NCODES - 1 : bi);
        ids[row] = b;
        outIds[row] = (float)b;
    }
}

// ---------------- kernel 7: gather z_q_st (f32) + loss partials (verified) --------
__global__ void k_gather(const float* __restrict__ zE, const float* __restrict__ cb,
                         const int* __restrict__ ids, float* __restrict__ outZ,
                         double* __restrict__ lossPart) {
    const int tid = threadIdx.x;
    double acc = 0.0;
#pragma unroll
    for (int it = 0; it < 4; ++it) {
        int chunk = blockIdx.x * 256 + tid + it * 1048576;
        int row   = chunk >> 7;
        int koff  = (chunk & 127) << 2;
        int id    = ids[row];
        id = id < 0 ? 0 : (id > NCODES - 1 ? NCODES - 1 : id);
        float4 ze = *(const float4*)(zE + ((size_t)row << 9) + koff);
        float4 zq = *(const float4*)(cb + ((size_t)id << 9) + koff);
        float d0 = __fsub_rn(zq.x, ze.x);
        float d1 = __fsub_rn(zq.y, ze.y);
        float d2 = __fsub_rn(zq.z, ze.z);
        float d3 = __fsub_rn(zq.w, ze.w);
        float4 v;
        v.x = __fadd_rn(ze.x, d0);
        v.y = __fadd_rn(ze.y, d1);
        v.z = __fadd_rn(ze.z, d2);
        v.w = __fadd_rn(ze.w, d3);
        *reinterpret_cast<float4*>(outZ + ((size_t)chunk << 2)) = v;
        acc += (double)d0 * d0 + (double)d1 * d1 + (double)d2 * d2 + (double)d3 * d3;
    }
    for (int off = 32; off; off >>= 1) acc += __shfl_down(acc, off);
    __shared__ double sred[4];
    if ((tid & 63) == 0) sred[tid >> 6] = acc;
    __syncthreads();
    if (tid == 0) lossPart[blockIdx.x] = (sred[0] + sred[1]) + (sred[2] + sred[3]);
}

// ---------------- kernel 8: final loss (verified) ----------------
__global__ void k_loss(const double* __restrict__ lossPart, float* __restrict__ outLoss) {
    const int tid = threadIdx.x;
    double acc = 0.0;
    for (int i = tid; i < 4096; i += 256) acc += lossPart[i];
    for (int off = 32; off; off >>= 1) acc += __shfl_down(acc, off);
    __shared__ double sred[4];
    if ((tid & 63) == 0) sred[tid >> 6] = acc;
    __syncthreads();
    if (tid == 0) {
        double mean = ((sred[0] + sred[1]) + (sred[2] + sred[3])) / 16777216.0;
        float cl = (float)mean;
        *outLoss = __fadd_rn(cl, __fmul_rn(0.25f, cl));
    }
}

extern "C" void kernel_launch(void* const* d_in, const int* in_sizes, int n_in,
                              void* d_out, int out_size, void* d_ws, size_t ws_size,
                              hipStream_t stream) {
    (void)in_sizes; (void)n_in; (void)out_size; (void)ws_size;
    const float* zE = (const float*)d_in[0];
    const float* cb = (const float*)d_in[1];
    float* out = (float*)d_out;
    char*  ws  = (char*)d_ws;
    char*  ob  = (char*)d_out;

    // ws scratch (small)
    float*  sq       = (float*)(ws + 0);              // 128 KiB
    float*  e2       = (float*)(ws + 131072);         // 32 KiB
    int*    ids      = (int*)(ws + 163840);           // 128 KiB
    float*  sabs     = (float*)(ws + 294912);         // 128 KiB
    int*    tileCnt  = (int*)(ws + 425984);           // 256 B
    float*  thr      = (float*)(ws + 430080);         // 128 KiB
    int*    cnt      = (int*)(ws + 561152);           // 128 KiB
    double* lossPart = (double*)(ws + 1343488);       // 32 KiB

    // big scratch inside d_out region 0 (fully overwritten by k_gather afterwards)
    _Float16* zh       = (_Float16*)(ob + 0);            // 32 MiB
    _Float16* ch       = (_Float16*)(ob + 33554432);     //  8 MiB
    float*    tmin     = (float*)(ob + 41943040);        //  8 MiB [tile][row]
    int*      tileRows = (int*)(ob + 50331648);          //  8 MiB
    int*      cands    = (int*)(ob + 58720256);          //  8 MiB (32768 x 64)

    k_rowsums<<<(ROWS + NCODES) / 4, 256, 0, stream>>>(zE, cb, sq, e2, sabs);
    k_half<<<(ROWS + NCODES) * (D / 8) / 256, 256, 0, stream>>>(zE, cb, zh, ch);
    k_mfma_min<<<8192, 256, 0, stream>>>(zh, ch, sq, e2, tmin);
    hipMemsetAsync(tileCnt, 0, 256, stream);
    hipMemsetAsync(cnt, 0, 131072, stream);
    k_select<<<ROWS / 256, 256, 0, stream>>>(tmin, sabs, thr, tileCnt, tileRows);
    k_mfma_cand<<<256, 256, 0, stream>>>(zh, ch, sq, e2, thr, tileCnt, tileRows,
                                         cnt, cands);
    k_rescore<<<ROWS / 4, 256, 0, stream>>>(zE, cb, sq, e2, cnt, cands,
                                            ids, out + 16777216);
    k_gather<<<4096, 256, 0, stream>>>(zE, cb, ids, out, lossPart);
    k_loss<<<1, 256, 0, stream>>>(lossPart, out + 16777216 + 32768);
}

// Round 17
// 1011.795 us; speedup vs baseline: 6.2196x; 1.3768x over previous
//
#include <hip/hip_runtime.h>

#define ROWS 32768      // B*T
#define D 512
#define NCODES 8192
#define KC 384          // OpenBLAS sgemm kc panel split (verified exact, rounds 4-16)
#define NTILES 64       // 8192 codes / 128
#define NSLOT 64

typedef _Float16 h8 __attribute__((ext_vector_type(8)));
typedef float f4v __attribute__((ext_vector_type(4)));

// ---------------- kernel 1: row sums (wave-per-row, np-pairwise-exact) ----------------
__global__ __launch_bounds__(256)
void k_rowsums(const float* __restrict__ zE, const float* __restrict__ cb,
               float* __restrict__ sq, float* __restrict__ e2,
               float* __restrict__ sabs) {
    const int wid  = blockIdx.x * 4 + (threadIdx.x >> 6);   // 0..40959
    const int lane = threadIdx.x & 63;
    const float* p = (wid < ROWS) ? zE + (size_t)wid * D
                                  : cb + (size_t)(wid - ROWS) * D;
    float v;
    if (lane < 32) {
        const int b = lane >> 3, j = lane & 7;
        const float* q = p + b * 128 + j;
        float r = __fmul_rn(q[0], q[0]);
#pragma unroll
        for (int i = 1; i < 16; ++i) {
            float t = q[i * 8];
            r = __fadd_rn(r, __fmul_rn(t, t));
        }
        v = r;
    } else {
        const int m = lane - 32;
        float sa = 0.0f;
#pragma unroll
        for (int i = 0; i < 16; ++i) sa += fabsf(p[i * 32 + m]);
        v = sa;
    }
    v = __fadd_rn(v, __shfl_xor(v, 1));
    v = __fadd_rn(v, __shfl_xor(v, 2));
    v = __fadd_rn(v, __shfl_xor(v, 4));
    v = __fadd_rn(v, __shfl_xor(v, 8));
    v = __fadd_rn(v, __shfl_xor(v, 16));
    float sa = __shfl(v, 32);
    if (lane == 0) {
        if (wid < ROWS) { sq[wid] = v; sabs[wid] = sa; }
        else            { e2[wid - ROWS] = v; }
    }
}

// ---------------- kernel 2: f32 -> f16 conversion (cb scaled by 2^12) ----------------
__global__ void k_half(const float* __restrict__ zE, const float* __restrict__ cb,
                       _Float16* __restrict__ zh, _Float16* __restrict__ ch) {
    int i = (blockIdx.x * 256 + threadIdx.x) * 8;
    if (i < ROWS * D) {
        float4 u = *(const float4*)(zE + i);
        float4 v = *(const float4*)(zE + i + 4);
        h8 o = {(_Float16)u.x, (_Float16)u.y, (_Float16)u.z, (_Float16)u.w,
                (_Float16)v.x, (_Float16)v.y, (_Float16)v.z, (_Float16)v.w};
        *(h8*)(zh + i) = o;
    } else {
        int j = i - ROWS * D;
        float4 u = *(const float4*)(cb + j);
        float4 v = *(const float4*)(cb + j + 4);
        h8 o = {(_Float16)(u.x * 4096.0f), (_Float16)(u.y * 4096.0f),
                (_Float16)(u.z * 4096.0f), (_Float16)(u.w * 4096.0f),
                (_Float16)(v.x * 4096.0f), (_Float16)(v.y * 4096.0f),
                (_Float16)(v.z * 4096.0f), (_Float16)(v.w * 4096.0f)};
        *(h8*)(ch + j) = o;
    }
}

// approx distance (deterministic; identical in both MFMA kernels)
__device__ __forceinline__ float dapprox(float s, float accv, float ecv) {
    float m = __fmul_rn(accv, 0.000244140625f);       // exact /4096
    return __fadd_rn(__fsub_rn(s, __fmul_rn(2.0f, m)), ecv);
}

// ---------------- kernel 3: fp16 MFMA pass 1 -> per-tile minima ----------------
// Double-buffered LDS staging via global_load_lds (width 16). Chunk layout is
// linear [frag][lane] because each lane's staging source == its own read addr.
// MFMA accumulate order identical to rounds 12-16 -> d~ bit-identical.
__global__ __launch_bounds__(256, 2)
void k_mfma_min(const _Float16* __restrict__ zh, const _Float16* __restrict__ ch,
                const float* __restrict__ sq, const float* __restrict__ e2,
                float* __restrict__ tmin) {
    __shared__ h8 AB[2 * 1536];   // [buf][A: 4w x 4a x 64 | B: 8b x 64] = 48 KiB

    const int p    = blockIdx.x;                      // 0..8191
    const int ct   = (p & 7) * 8 + ((p >> 3) & 7);    // code tile 0..63 (XCD-local)
    const int rt   = p >> 6;                          // row tile 0..127
    const int wv   = threadIdx.x >> 6;
    const int wvu  = __builtin_amdgcn_readfirstlane(wv);   // uniform for LDS dest
    const int lane = threadIdx.x & 63;
    const int l15  = lane & 15;
    const int lk   = lane >> 4;
    const int rw   = rt * 256 + wvu * 64;
    const int cw   = ct * 128;

    f4v acc[4][8];
#pragma unroll
    for (int a = 0; a < 4; ++a)
#pragma unroll
        for (int b = 0; b < 8; ++b) acc[a][b] = (f4v){0.f, 0.f, 0.f, 0.f};

#define STAGE(buf, k0c)                                                              \
    {                                                                                \
        _Pragma("unroll")                                                            \
        for (int a = 0; a < 4; ++a) {                                                \
            const _Float16* src = zh + (size_t)(rw + a * 16 + l15) * D + (k0c) + lk * 8; \
            __builtin_amdgcn_global_load_lds(                                        \
                (const __attribute__((address_space(1))) void*)(const void*)src,    \
                (__attribute__((address_space(3))) void*)(void*)&AB[(buf) * 1536 + wvu * 256 + a * 64], \
                16, 0, 0);                                                           \
        }                                                                            \
        _Pragma("unroll")                                                            \
        for (int j = 0; j < 2; ++j) {                                                \
            const int bb = wvu * 2 + j;                                              \
            const _Float16* src = ch + (size_t)(cw + bb * 16 + l15) * D + (k0c) + lk * 8; \
            __builtin_amdgcn_global_load_lds(                                        \
                (const __attribute__((address_space(1))) void*)(const void*)src,    \
                (__attribute__((address_space(3))) void*)(void*)&AB[(buf) * 1536 + 1024 + bb * 64], \
                16, 0, 0);                                                           \
        }                                                                            \
    }

    STAGE(0, 0);
    int cur = 0;
#pragma unroll 1
    for (int ks = 0; ks < 16; ++ks) {                 // k0 = ks*32, ascending
        __syncthreads();                              // staged buf `cur` ready
        if (ks < 15) STAGE(cur ^ 1, (ks + 1) * 32);   // async prefetch next
        h8 bf[8];
#pragma unroll
        for (int b = 0; b < 8; ++b) bf[b] = AB[cur * 1536 + 1024 + b * 64 + lane];
#pragma unroll
        for (int a = 0; a < 4; ++a) {
            h8 af = AB[cur * 1536 + wvu * 256 + a * 64 + lane];
#pragma unroll
            for (int b = 0; b < 8; ++b)
                acc[a][b] = __builtin_amdgcn_mfma_f32_16x16x32_f16(af, bf[b], acc[a][b], 0, 0, 0);
        }
        cur ^= 1;
    }
#undef STAGE

#pragma unroll
    for (int a = 0; a < 4; ++a) {
        const int r0 = rw + a * 16 + lk * 4;
        float s0 = sq[r0 + 0], s1 = sq[r0 + 1], s2 = sq[r0 + 2], s3 = sq[r0 + 3];
        float rm[4] = {INFINITY, INFINITY, INFINITY, INFINITY};
#pragma unroll
        for (int b = 0; b < 8; ++b) {
            float ecv = e2[cw + b * 16 + l15];
            rm[0] = fminf(rm[0], dapprox(s0, acc[a][b][0], ecv));
            rm[1] = fminf(rm[1], dapprox(s1, acc[a][b][1], ecv));
            rm[2] = fminf(rm[2], dapprox(s2, acc[a][b][2], ecv));
            rm[3] = fminf(rm[3], dapprox(s3, acc[a][b][3], ecv));
        }
#pragma unroll
        for (int jj = 0; jj < 4; ++jj) {
            float v = rm[jj];
            v = fminf(v, __shfl_xor(v, 1));
            v = fminf(v, __shfl_xor(v, 2));
            v = fminf(v, __shfl_xor(v, 4));
            v = fminf(v, __shfl_xor(v, 8));
            if (l15 == 0) tmin[(size_t)ct * ROWS + (r0 + jj)] = v;   // [tile][row]
        }
    }
}

// ---------------- kernel 4: per-row threshold + per-tile row lists ----------------
__global__ void k_select(const float* __restrict__ tmin, const float* __restrict__ sabs,
                         float* __restrict__ thr, int* __restrict__ tileCnt,
                         int* __restrict__ tileRows) {
    int row = blockIdx.x * 256 + threadIdx.x;
    if (row >= ROWS) return;
    float g = tmin[row];                              // tile 0
#pragma unroll 8
    for (int i = 1; i < NTILES; ++i) g = fminf(g, tmin[(size_t)i * ROWS + row]);
    float th = g + (sabs[row] * 8e-7f + 6e-4f);       // WIN = 2*err bound (verified)
    thr[row] = th;
    for (int i = 0; i < NTILES; ++i)
        if (tmin[(size_t)i * ROWS + row] <= th) {
            int sl = atomicAdd(&tileCnt[i], 1);
            tileRows[(size_t)i * ROWS + sl] = row;
        }
}

// ---------------- kernel 5: fp16 MFMA pass 2 (qualifying pairs only) -> candidates ----
__global__ __launch_bounds__(256, 2)
void k_mfma_cand(const _Float16* __restrict__ zh, const _Float16* __restrict__ ch,
                 const float* __restrict__ sq, const float* __restrict__ e2,
                 const float* __restrict__ thr, const int* __restrict__ tileCnt,
                 const int* __restrict__ tileRows, int* __restrict__ cnt,
                 int* __restrict__ cands) {
    const int p     = blockIdx.x;                     // 0..511
    const int t     = (p & 7) * 8 + ((p >> 3) & 7);   // tile, XCD-pinned (= pass-1 map)
    const int chunk = p >> 6;                         // 0..7
    const int wave  = threadIdx.x >> 6;
    const int lane  = threadIdx.x & 63;
    const int l15   = lane & 15;
    const int lk    = lane >> 4;
    const int cw    = t * 128;
    const int n     = tileCnt[t];
    const int ngrp  = (n + 63) >> 6;

    for (int g = chunk * 4 + wave; g < ngrp; g += 32) {
        int gi = g * 64 + lane;
        int myrow = (gi < n) ? tileRows[(size_t)t * ROWS + gi] : -1;

        f4v acc[4][8];
#pragma unroll
        for (int a = 0; a < 4; ++a)
#pragma unroll
            for (int b = 0; b < 8; ++b) acc[a][b] = (f4v){0.f, 0.f, 0.f, 0.f};

#pragma unroll 2
        for (int k0 = 0; k0 < D; k0 += 32) {
            h8 bf[8];
#pragma unroll
            for (int b = 0; b < 8; ++b)
                bf[b] = *(const h8*)(ch + (size_t)(cw + b * 16 + l15) * D + k0 + lk * 8);
#pragma unroll
            for (int a = 0; a < 4; ++a) {
                int ra = __shfl(myrow, a * 16 + l15);
                ra = ra < 0 ? 0 : ra;
                h8 af = *(const h8*)(zh + (size_t)ra * D + k0 + lk * 8);
#pragma unroll
                for (int b = 0; b < 8; ++b)
                    acc[a][b] = __builtin_amdgcn_mfma_f32_16x16x32_f16(af, bf[b], acc[a][b], 0, 0, 0);
            }
        }

#pragma unroll
        for (int a = 0; a < 4; ++a) {
#pragma unroll
            for (int jj = 0; jj < 4; ++jj) {
                int rowv = __shfl(myrow, a * 16 + lk * 4 + jj);
                if (rowv < 0) continue;
                float s  = sq[rowv];
                float th = thr[rowv];
#pragma unroll
                for (int b = 0; b < 8; ++b) {
                    int c = cw + b * 16 + l15;
                    float d = dapprox(s, acc[a][b][jj], e2[c]);
                    if (d <= th) {
                        int sl = atomicAdd(&cnt[rowv], 1);
                        if (sl < NSLOT) cands[(size_t)rowv * NSLOT + sl] = c;
                    }
                }
            }
        }
    }
}

// exact distance: verified dual-chain, sequential ascending-k FMA
__device__ __forceinline__ float exact_d(const float* __restrict__ xr,
                                         const float* __restrict__ er,
                                         float s, float ev) {
    float m1 = 0.0f, m2 = 0.0f;
#pragma unroll 8
    for (int k = 0; k < KC; ++k) m1 = __builtin_fmaf(xr[k], er[k], m1);
#pragma unroll 8
    for (int k = KC; k < D; ++k) m2 = __builtin_fmaf(xr[k], er[k], m2);
    float m = __fadd_rn(m1, m2);
    return __fadd_rn(__fsub_rn(s, __fmul_rn(2.0f, m)), ev);
}

// ---------------- kernel 6: exact rescore (wave-per-row, LDS-staged x) ----------------
__global__ __launch_bounds__(256)
void k_rescore(const float* __restrict__ zE, const float* __restrict__ cb,
               const float* __restrict__ sq, const float* __restrict__ e2,
               const int* __restrict__ cnt, const int* __restrict__ cands,
               int* __restrict__ ids, float* __restrict__ outIds) {
    __shared__ float xs[4][D];
    const int wave = threadIdx.x >> 6;
    const int lane = threadIdx.x & 63;
    const int row  = blockIdx.x * 4 + wave;

    const float* xr = zE + (size_t)row * D;
    *(float4*)&xs[wave][lane * 8]     = *(const float4*)(xr + lane * 8);
    *(float4*)&xs[wave][lane * 8 + 4] = *(const float4*)(xr + lane * 8 + 4);
    __syncthreads();

    float s = sq[row];
    int   n = cnt[row];
    float bd = INFINITY;
    int   bi = NCODES - 1;
    if (n <= NSLOT) {
        for (int t = lane; t < n; t += 64) {
            int c = cands[(size_t)row * NSLOT + t];
            float d = exact_d(xs[wave], cb + (size_t)c * D, s, e2[c]);
            if (d < bd || (d == bd && c < bi)) { bd = d; bi = c; }
        }
    } else {                                          // sound fallback (never expected)
        for (int c = lane; c < NCODES; c += 64) {
            float d = exact_d(xs[wave], cb + (size_t)c * D, s, e2[c]);
            if (d < bd || (d == bd && c < bi)) { bd = d; bi = c; }
        }
    }
#pragma unroll
    for (int off = 32; off; off >>= 1) {
        float v2 = __shfl_xor(bd, off);
        int   x2 = __shfl_xor(bi, off);
        if (v2 < bd || (v2 == bd && x2 < bi)) { bd = v2; bi = x2; }
    }
    if (lane == 0) {
        int b = bi < 0 ? 0 : (bi > NCODES - 1 ? NCODES - 1 : bi);
        ids[row] = b;
        outIds[row] = (float)b;
    }
}

// ---------------- kernel 7: gather z_q_st (f32) + loss partials (verified) --------
__global__ void k_gather(const float* __restrict__ zE, const float* __restrict__ cb,
                         const int* __restrict__ ids, float* __restrict__ outZ,
                         double* __restrict__ lossPart) {
    const int tid = threadIdx.x;
    double acc = 0.0;
#pragma unroll
    for (int it = 0; it < 4; ++it) {
        int chunk = blockIdx.x * 256 + tid + it * 1048576;
        int row   = chunk >> 7;
        int koff  = (chunk & 127) << 2;
        int id    = ids[row];
        id = id < 0 ? 0 : (id > NCODES - 1 ? NCODES - 1 : id);
        float4 ze = *(const float4*)(zE + ((size_t)row << 9) + koff);
        float4 zq = *(const float4*)(cb + ((size_t)id << 9) + koff);
        float d0 = __fsub_rn(zq.x, ze.x);
        float d1 = __fsub_rn(zq.y, ze.y);
        float d2 = __fsub_rn(zq.z, ze.z);
        float d3 = __fsub_rn(zq.w, ze.w);
        float4 v;
        v.x = __fadd_rn(ze.x, d0);
        v.y = __fadd_rn(ze.y, d1);
        v.z = __fadd_rn(ze.z, d2);
        v.w = __fadd_rn(ze.w, d3);
        *reinterpret_cast<float4*>(outZ + ((size_t)chunk << 2)) = v;
        acc += (double)d0 * d0 + (double)d1 * d1 + (double)d2 * d2 + (double)d3 * d3;
    }
    for (int off = 32; off; off >>= 1) acc += __shfl_down(acc, off);
    __shared__ double sred[4];
    if ((tid & 63) == 0) sred[tid >> 6] = acc;
    __syncthreads();
    if (tid == 0) lossPart[blockIdx.x] = (sred[0] + sred[1]) + (sred[2] + sred[3]);
}

// ---------------- kernel 8: final loss (verified) ----------------
__global__ void k_loss(const double* __restrict__ lossPart, float* __restrict__ outLoss) {
    const int tid = threadIdx.x;
    double acc = 0.0;
    for (int i = tid; i < 4096; i += 256) acc += lossPart[i];
    for (int off = 32; off; off >>= 1) acc += __shfl_down(acc, off);
    __shared__ double sred[4];
    if ((tid & 63) == 0) sred[tid >> 6] = acc;
    __syncthreads();
    if (tid == 0) {
        double mean = ((sred[0] + sred[1]) + (sred[2] + sred[3])) / 16777216.0;
        float cl = (float)mean;
        *outLoss = __fadd_rn(cl, __fmul_rn(0.25f, cl));
    }
}

extern "C" void kernel_launch(void* const* d_in, const int* in_sizes, int n_in,
                              void* d_out, int out_size, void* d_ws, size_t ws_size,
                              hipStream_t stream) {
    (void)in_sizes; (void)n_in; (void)out_size; (void)ws_size;
    const float* zE = (const float*)d_in[0];
    const float* cb = (const float*)d_in[1];
    float* out = (float*)d_out;
    char*  ws  = (char*)d_ws;
    char*  ob  = (char*)d_out;

    // ws scratch (small)
    float*  sq       = (float*)(ws + 0);              // 128 KiB
    float*  e2       = (float*)(ws + 131072);         // 32 KiB
    int*    ids      = (int*)(ws + 163840);           // 128 KiB
    float*  sabs     = (float*)(ws + 294912);         // 128 KiB
    int*    tileCnt  = (int*)(ws + 425984);           // 256 B
    float*  thr      = (float*)(ws + 430080);         // 128 KiB
    int*    cnt      = (int*)(ws + 561152);           // 128 KiB
    double* lossPart = (double*)(ws + 1343488);       // 32 KiB

    // big scratch inside d_out region 0 (fully overwritten by k_gather afterwards)
    _Float16* zh       = (_Float16*)(ob + 0);            // 32 MiB
    _Float16* ch       = (_Float16*)(ob + 33554432);     //  8 MiB
    float*    tmin     = (float*)(ob + 41943040);        //  8 MiB [tile][row]
    int*      tileRows = (int*)(ob + 50331648);          //  8 MiB
    int*      cands    = (int*)(ob + 58720256);          //  8 MiB (32768 x 64)

    k_rowsums<<<(ROWS + NCODES) / 4, 256, 0, stream>>>(zE, cb, sq, e2, sabs);
    k_half<<<(ROWS + NCODES) * (D / 8) / 256, 256, 0, stream>>>(zE, cb, zh, ch);
    k_mfma_min<<<8192, 256, 0, stream>>>(zh, ch, sq, e2, tmin);
    hipMemsetAsync(tileCnt, 0, 256, stream);
    hipMemsetAsync(cnt, 0, 131072, stream);
    k_select<<<ROWS / 256, 256, 0, stream>>>(tmin, sabs, thr, tileCnt, tileRows);
    k_mfma_cand<<<512, 256, 0, stream>>>(zh, ch, sq, e2, thr, tileCnt, tileRows,
                                         cnt, cands);
    k_rescore<<<ROWS / 4, 256, 0, stream>>>(zE, cb, sq, e2, cnt, cands,
                                            ids, out + 16777216);
    k_gather<<<4096, 256, 0, stream>>>(zE, cb, ids, out, lossPart);
    k_loss<<<1, 256, 0, stream>>>(lossPart, out + 16777216 + 32768);
}